// Round 6
// baseline (175.795 us; speedup 1.0000x reference)
//
#include <hip/hip_runtime.h>
#include <hip/hip_bf16.h>

#define D_MODEL 256
#define NUM_HEADS 8
#define DIM_HEAD 32
#define SEQ 4096
#define BATCH 2
#define NROWS (BATCH * SEQ)              // 8192
#define LN_EPS 1e-6f
#define MASK_BIAS -1.0e9f
#define SCALE 0.17677669529663687f      // 1/sqrt(32)
#define LOG2E 1.4426950408889634f
#define QSCALE (SCALE * LOG2E)          // folded into Q at projection time

typedef __attribute__((ext_vector_type(8))) short short8;   // 8 bf16 (4 VGPRs)
typedef __attribute__((ext_vector_type(4))) float f32x4;    // MFMA C/D

// fp32 -> bf16 bits (RNE)
static __device__ __forceinline__ unsigned short f2b(float f) {
    union { __hip_bfloat16 b; unsigned short u; } cv;
    cv.b = __float2bfloat16(f);
    return cv.u;
}
// packed fp32 pair -> bf16x2 (RNE), lo in low 16 bits
static __device__ __forceinline__ unsigned int pk_bf16(float lo, float hi) {
    union { __hip_bfloat162 v; unsigned int u; } cv;
    cv.v = __float22bfloat162_rn(make_float2(lo, hi));
    return cv.u;
}
// raw v_exp_f32: 1 instruction (no libm fixup)
static __device__ __forceinline__ float exp2_raw(float x) {
#if __has_builtin(__builtin_amdgcn_exp2f)
    return __builtin_amdgcn_exp2f(x);
#else
    float r;
    asm volatile("v_exp_f32 %0, %1" : "=v"(r) : "v"(x));
    return r;
#endif
}
// async global->LDS, 16B per lane; LDS dest = uniform base + lane*16
static __device__ __forceinline__ void load_lds16(const void* g, void* l) {
    __builtin_amdgcn_global_load_lds(
        (const __attribute__((address_space(1))) unsigned int*)g,
        (__attribute__((address_space(3))) unsigned int*)l, 16, 0, 0);
}

// ---------------------------------------------------------------------------
// Kernel 0: prep. Blocks 0..767: Wt[n_cat][k] = W_w[k][n] (bf16) + bias.
// Blocks 768..799: T2 = pad * (-1e9*scale*log2e).
// ---------------------------------------------------------------------------
__global__ __launch_bounds__(256) void prep_kernel(
    const float* __restrict__ Wq, const float* __restrict__ Wk,
    const float* __restrict__ Wv,
    const float* __restrict__ bq, const float* __restrict__ bk,
    const float* __restrict__ bv,
    const float* __restrict__ pad,
    unsigned short* __restrict__ Wt, float* __restrict__ biasc,
    float* __restrict__ T2)
{
    const int blk = blockIdx.x;
    const int t = threadIdx.x;
    if (blk < 768) {
        const int w = blk >> 8;          // 0=Q 1=K 2=V
        const int k = blk & 255;         // input row (contraction index)
        const float* W = (w == 0) ? Wq : (w == 1) ? Wk : Wv;
        Wt[(size_t)(w * 256 + t) * 256 + k] = f2b(W[(size_t)k * 256 + t]);
        if (k == 0) {
            const float* bb = (w == 0) ? bq : (w == 1) ? bk : bv;
            biasc[w * 256 + t] = bb[t];
        }
    } else {
        const int i = (blk - 768) * 256 + t;
        T2[i] = pad[i] * (MASK_BIAS * SCALE * LOG2E);
    }
}

// ---------------------------------------------------------------------------
// Kernel 1: QKV projection as bf16 MFMA GEMM.
// Q output is pre-scaled by QSCALE = SCALE*LOG2E, so the attn kernel's
// QK^T MFMA result is already in exp2-argument units.
// ---------------------------------------------------------------------------
__global__ __launch_bounds__(256) void qkv_mfma_kernel(
    const float* __restrict__ x, const unsigned short* __restrict__ Wt,
    const float* __restrict__ biasc,
    unsigned short* __restrict__ Qh, unsigned short* __restrict__ Kh,
    unsigned short* __restrict__ Vt)
{
    const int lane = threadIdx.x & 63;
    const int wid  = threadIdx.x >> 6;
    const int c    = lane & 15;
    const int quad = lane >> 4;

    const int r0 = (blockIdx.x >> 3) * 64 + wid * 16;   // wave row base
    const int n0 = (blockIdx.x & 7) * 96;               // wave col base

    f32x4 acc[6];
    float bias[6];
    #pragma unroll
    for (int t = 0; t < 6; t++) {
        acc[t] = (f32x4){0.f, 0.f, 0.f, 0.f};
        bias[t] = biasc[n0 + 16 * t + c];
    }

    const float* xp0 = x + (size_t)(r0 + c) * D_MODEL + quad * 8;
    const unsigned short* wp0 = Wt + (size_t)(n0 + c) * 256 + quad * 8;

    for (int k0 = 0; k0 < 256; k0 += 32) {
        const float4 a0 = *(const float4*)(xp0 + k0);
        const float4 a1 = *(const float4*)(xp0 + k0 + 4);
        union { unsigned int u[4]; short8 s; } af;
        af.u[0] = pk_bf16(a0.x, a0.y);
        af.u[1] = pk_bf16(a0.z, a0.w);
        af.u[2] = pk_bf16(a1.x, a1.y);
        af.u[3] = pk_bf16(a1.z, a1.w);
        #pragma unroll
        for (int t = 0; t < 6; t++) {
            const short8 bf = *(const short8*)(wp0 + (size_t)(16 * t) * 256 + k0);
            acc[t] = __builtin_amdgcn_mfma_f32_16x16x32_bf16(af.s, bf, acc[t], 0, 0, 0);
        }
    }

    #pragma unroll
    for (int t = 0; t < 6; t++) {
        const int col = n0 + 16 * t;          // tile col base (multiple of 16)
        const int mm  = col >> 8;             // 0=Q 1=K 2=V (uniform per tile)
        const int dim = (col & 255) + c;
        const int h = dim >> 5, d = dim & 31;
        const int row = r0 + quad * 4;        // rows row..row+3 (same batch)
        const int bb = row >> 12;
        const int s  = row & (SEQ - 1);
        const size_t bh = (size_t)(bb * NUM_HEADS + h);
        float v0 = acc[t][0] + bias[t];
        float v1 = acc[t][1] + bias[t];
        float v2 = acc[t][2] + bias[t];
        float v3 = acc[t][3] + bias[t];
        if (mm == 2) {
            uint2 pk = make_uint2(pk_bf16(v0, v1), pk_bf16(v2, v3));
            *(uint2*)(Vt + (bh * DIM_HEAD + d) * SEQ + s) = pk;
        } else {
            if (mm == 0) {                    // pre-scale Q by SCALE*LOG2E
                v0 *= QSCALE; v1 *= QSCALE; v2 *= QSCALE; v3 *= QSCALE;
            }
            unsigned short* P = (mm == 0 ? Qh : Kh) + (bh * SEQ + s) * DIM_HEAD + d;
            P[0]  = f2b(v0);
            P[32] = f2b(v1);
            P[64] = f2b(v2);
            P[96] = f2b(v3);
        }
    }
}

// ---------------------------------------------------------------------------
// Kernel 2: MFMA flash attention v11 — T (mask bias) in REGISTERS, not LDS.
// R17 theory: DS pipe is the largest per-CU term (~31 µs: 12 ds_read_b128
// per wave-round x 1.57M); 4 of those 12 were T reads — but T2 is a 32KB
// L1-resident array that gains nothing from LDS amortization. Move T to
// per-wave global_load_dwordx4 (VMEM pipe, L1 hits), double-buffered in
// named regs (ping-pong via unroll-2). DS-pipe instrs/round: 12 -> 8.
// Staging becomes uniform (no wave-7 T op): waits are vmcnt(2) everywhere.
// FIFO proof (steady state, oldest->newest): [stage(r):2, T(r):4,
// stage(r+1):2] -> keep-newest-2 drains exactly stage(r)+T(r).
// sched_barrier(0) pins Tload-before-stage issue order. s_setprio(1) wraps
// the MFMA clusters (T5). Everything else per R16 (128-key rounds, 8 waves,
// triple-buffered counted-vmcnt staging, LDS combine for key-split halves).
// ---------------------------------------------------------------------------
__global__ __launch_bounds__(512, 4) void attn_mfma_kernel(
    const unsigned short* __restrict__ Qh, const unsigned short* __restrict__ Kh,
    const unsigned short* __restrict__ Vt, const float* __restrict__ T2,
    float* __restrict__ O)
{
    // layout (bytes): K 3x8KB @0, V 3x8KB @24576.
    // combine scratch (20480B) overlays K region after the loop drains.
    __shared__ __align__(16) unsigned char smem[49152];
    unsigned short* smem_s = (unsigned short*)smem;

    const int lane = threadIdx.x & 63;
    const int wid  = threadIdx.x >> 6;     // 0..7
    const int cwid = wid & 3;              // query-tile id within block
    const int shalf = wid >> 2;            // which 64-key half this wave owns
    const int c    = lane & 15;
    const int quad = lane >> 4;

    const int gw = blockIdx.x;                   // 0..511
    const int q0 = (gw & 31) * 128;              // 128 queries per block
    const int h  = (gw >> 5) & (NUM_HEADS - 1);
    const int b  = gw >> 8;
    const size_t bh = (size_t)(b * NUM_HEADS + h);

    const int perm = ((c & 12) << 1) | (c & 3);  // pi(c)

    const unsigned short* Kb = Kh + bh * SEQ * DIM_HEAD;
    const unsigned short* Vb = Vt + bh * DIM_HEAD * SEQ;
    const float* Tg = T2 + (size_t)b * SEQ;

    // wave's 32 queries: q0 + cwid*32 + {c, 16+c}  (shared with wave cwid+4)
    const int qrow = q0 + cwid * 32;
    const short8 qfA = *(const short8*)(Qh + (bh * SEQ + qrow + c) * DIM_HEAD + quad * 8);
    const short8 qfB = *(const short8*)(Qh + (bh * SEQ + qrow + 16 + c) * DIM_HEAD + quad * 8);

    union { unsigned int u[4]; short8 s; } ones;
    ones.u[0] = ones.u[1] = ones.u[2] = ones.u[3] = 0x3F803F80u;  // bf16 1.0 x2

    // loop-invariant LDS read offsets (elements). f(key)=((key>>1)^(key>>3))&3
    // is invariant to key += 32, so kA/kB generalize to sub s via +s*1024.
    // V key-group swizzle: address = vbase ^ (s<<5).
    const int f0 = ((perm >> 1) ^ (perm >> 3)) & 3;
    const int f1 = (((perm + 4) >> 1) ^ ((perm + 4) >> 3)) & 3;
    const int kA = perm * 32 + ((quad ^ f0) << 3);        // + s*1024
    const int kB = (perm + 4) * 32 + ((quad ^ f1) << 3);
    const int g0 = quad ^ (c & 7);
    const int vbase0 = c * 128 + (g0 << 3);               // ^ (s<<5)
    const int vbase1 = (16 + c) * 128 + (g0 << 3);        // (16+c)&7 == c&7

    // staging lane constants
    const int skey = (lane >> 2);                // K: + j*16
    const int sgK  = lane & 3;
    const int sdim = lane >> 4;                  // V: + j*4
    const int sgV  = lane & 15;

    f32x4 oA0 = {0.f,0.f,0.f,0.f}, oA1 = {0.f,0.f,0.f,0.f};
    f32x4 oB0 = {0.f,0.f,0.f,0.f}, oB1 = {0.f,0.f,0.f,0.f};
    f32x4 laccA = {0.f,0.f,0.f,0.f}, laccB = {0.f,0.f,0.f,0.f};

    // stage 128-key chunk ch into buffer pb. Uniform 2 VMEM ops per wave:
    // waves 0-3: K tiles j=wid*2+jj; waves 4-7: V tiles j=(wid-4)*2+jj.
    auto stage = [&](int ch, int pb) {
        const int s0 = ch * 128;
        if (wid < 4) {
            #pragma unroll
            for (int jj = 0; jj < 2; jj++) {
                const int j = wid * 2 + jj;
                const int key = j * 16 + skey;
                const int f = ((key >> 1) ^ (key >> 3)) & 3;
                load_lds16(Kb + (size_t)(s0 + key) * 32 + ((sgK ^ f) << 3),
                           &smem_s[pb * 4096 + j * 512]);
            }
        } else {
            #pragma unroll
            for (int jj = 0; jj < 2; jj++) {
                const int j = (wid - 4) * 2 + jj;
                const int dim = j * 4 + sdim;
                load_lds16(Vb + (size_t)dim * SEQ + s0 + ((sgV ^ (dim & 7)) << 3),
                           &smem_s[12288 + pb * 4096 + j * 512]);
            }
        }
    };

    // one 32-key sub-chunk s from buffer pb; T (regs) folded in as MFMA C.
    auto sub = [&](int pb, int s, f32x4 c0, f32x4 c1) {
        const short8 kf0 = *(const short8*)&smem_s[pb * 4096 + s * 1024 + kA];
        const short8 kf1 = *(const short8*)&smem_s[pb * 4096 + s * 1024 + kB];
        const short8 vf0 = *(const short8*)&smem_s[12288 + pb * 4096 + (vbase0 ^ (s << 5))];
        const short8 vf1 = *(const short8*)&smem_s[12288 + pb * 4096 + (vbase1 ^ (s << 5))];

        __builtin_amdgcn_s_setprio(1);
        const f32x4 sA0 = __builtin_amdgcn_mfma_f32_16x16x32_bf16(kf0, qfA, c0, 0, 0, 0);
        const f32x4 sA1 = __builtin_amdgcn_mfma_f32_16x16x32_bf16(kf1, qfA, c1, 0, 0, 0);
        const f32x4 sB0 = __builtin_amdgcn_mfma_f32_16x16x32_bf16(kf0, qfB, c0, 0, 0, 0);
        const f32x4 sB1 = __builtin_amdgcn_mfma_f32_16x16x32_bf16(kf1, qfB, c1, 0, 0, 0);
        __builtin_amdgcn_s_setprio(0);

        union { unsigned int u[4]; short8 s8; } pfA, pfB;
        {
            float p0 = exp2_raw(sA0[0]), p1 = exp2_raw(sA0[1]);
            float p2 = exp2_raw(sA0[2]), p3 = exp2_raw(sA0[3]);
            float p4 = exp2_raw(sA1[0]), p5 = exp2_raw(sA1[1]);
            float p6 = exp2_raw(sA1[2]), p7 = exp2_raw(sA1[3]);
            pfA.u[0] = pk_bf16(p0, p1);
            pfA.u[1] = pk_bf16(p2, p3);
            pfA.u[2] = pk_bf16(p4, p5);
            pfA.u[3] = pk_bf16(p6, p7);
        }
        {
            float p0 = exp2_raw(sB0[0]), p1 = exp2_raw(sB0[1]);
            float p2 = exp2_raw(sB0[2]), p3 = exp2_raw(sB0[3]);
            float p4 = exp2_raw(sB1[0]), p5 = exp2_raw(sB1[1]);
            float p6 = exp2_raw(sB1[2]), p7 = exp2_raw(sB1[3]);
            pfB.u[0] = pk_bf16(p0, p1);
            pfB.u[1] = pk_bf16(p2, p3);
            pfB.u[2] = pk_bf16(p4, p5);
            pfB.u[3] = pk_bf16(p6, p7);
        }

        __builtin_amdgcn_s_setprio(1);
        laccA = __builtin_amdgcn_mfma_f32_16x16x32_bf16(ones.s, pfA.s8, laccA, 0, 0, 0);
        laccB = __builtin_amdgcn_mfma_f32_16x16x32_bf16(ones.s, pfB.s8, laccB, 0, 0, 0);
        oA0   = __builtin_amdgcn_mfma_f32_16x16x32_bf16(vf0,   pfA.s8, oA0,   0, 0, 0);
        oA1   = __builtin_amdgcn_mfma_f32_16x16x32_bf16(vf1,   pfA.s8, oA1,   0, 0, 0);
        oB0   = __builtin_amdgcn_mfma_f32_16x16x32_bf16(vf0,   pfB.s8, oB0,   0, 0, 0);
        oB1   = __builtin_amdgcn_mfma_f32_16x16x32_bf16(vf1,   pfB.s8, oB1,   0, 0, 0);
        __builtin_amdgcn_s_setprio(0);
    };

    int rb = 0;          // read buffer  = round % 3
    int sb = 2;          // stage buffer = (round+2) % 3

    // round r: consume T regs c** (round r), prefetch T(tch=r+1) into n**,
    // stage chunk r+2, compute chunk r.
    auto round = [&](f32x4& c00, f32x4& c01, f32x4& c10, f32x4& c11,
                     f32x4& n00, f32x4& n01, f32x4& n10, f32x4& n11, int tch) {
        asm volatile("s_waitcnt vmcnt(2) lgkmcnt(0)" ::: "memory");
        __builtin_amdgcn_s_barrier();
        __builtin_amdgcn_sched_barrier(0);
        const float* tp = Tg + tch * 128 + shalf * 64 + quad * 8;
        n00 = *(const f32x4*)(tp);
        n01 = *(const f32x4*)(tp + 4);
        n10 = *(const f32x4*)(tp + 32);
        n11 = *(const f32x4*)(tp + 36);
        __builtin_amdgcn_sched_barrier(0);
        stage((tch + 1) & 31, sb);       // overwrite buf[(r-1)%3]
        __builtin_amdgcn_sched_barrier(0);
        sub(rb, shalf * 2,     c00, c01);
        sub(rb, shalf * 2 + 1, c10, c11);
        rb = (rb == 2) ? 0 : rb + 1;
        sb = (sb == 2) ? 0 : sb + 1;
    };

    // prologue: T(0) regs first, then prefetch chunks 0 and 1.
    f32x4 ta00, ta01, ta10, ta11, tb00, tb01, tb10, tb11;
    {
        const float* tp = Tg + shalf * 64 + quad * 8;
        ta00 = *(const f32x4*)(tp);
        ta01 = *(const f32x4*)(tp + 4);
        ta10 = *(const f32x4*)(tp + 32);
        ta11 = *(const f32x4*)(tp + 36);
    }
    __builtin_amdgcn_sched_barrier(0);
    stage(0, 0);
    stage(1, 1);

    for (int rr = 0; rr < 16; ++rr) {
        round(ta00, ta01, ta10, ta11, tb00, tb01, tb10, tb11, (2 * rr + 1) & 31);
        round(tb00, tb01, tb10, tb11, ta00, ta01, ta10, ta11, (2 * rr + 2) & 31);
    }

    // drain ALL in-flight staging (wrap prefetches included) before reusing
    // the K LDS region as combine scratch.
    asm volatile("s_waitcnt vmcnt(0) lgkmcnt(0)" ::: "memory");
    __builtin_amdgcn_s_barrier();

    float* CS = (float*)smem;            // 256 slots x 20 floats = 20480 B
    if (wid >= 4) {
        const int slot = ((cwid * 64) + lane) * 20;
        *(f32x4*)&CS[slot + 0]  = oA0;
        *(f32x4*)&CS[slot + 4]  = oA1;
        *(f32x4*)&CS[slot + 8]  = oB0;
        *(f32x4*)&CS[slot + 12] = oB1;
        CS[slot + 16] = laccA[0];
        CS[slot + 17] = laccB[0];
    }
    asm volatile("s_waitcnt lgkmcnt(0)" ::: "memory");
    __builtin_amdgcn_s_barrier();
    if (wid < 4) {
        const int slot = ((cwid * 64) + lane) * 20;
        const f32x4 pA0 = *(const f32x4*)&CS[slot + 0];
        const f32x4 pA1 = *(const f32x4*)&CS[slot + 4];
        const f32x4 pB0 = *(const f32x4*)&CS[slot + 8];
        const f32x4 pB1 = *(const f32x4*)&CS[slot + 12];
        const float invA = 1.0f / (laccA[0] + CS[slot + 16]);
        const float invB = 1.0f / (laccB[0] + CS[slot + 17]);
        oA0 += pA0; oA1 += pA1; oB0 += pB0; oB1 += pB1;

        float* opA = O + ((size_t)(b * SEQ) + qrow + c) * D_MODEL + h * DIM_HEAD + quad * 4;
        float* opB = O + ((size_t)(b * SEQ) + qrow + 16 + c) * D_MODEL + h * DIM_HEAD + quad * 4;
        *(float4*)opA        = make_float4(oA0[0]*invA, oA0[1]*invA, oA0[2]*invA, oA0[3]*invA);
        *(float4*)(opA + 16) = make_float4(oA1[0]*invA, oA1[1]*invA, oA1[2]*invA, oA1[3]*invA);
        *(float4*)opB        = make_float4(oB0[0]*invB, oB0[1]*invB, oB0[2]*invB, oB0[3]*invB);
        *(float4*)(opB + 16) = make_float4(oB1[0]*invB, oB1[1]*invB, oB1[2]*invB, oB1[3]*invB);
    }
}

// ---------------------------------------------------------------------------
// Kernel 3: residual add + LayerNorm IN PLACE on d_out (fp32 -> fp32).
// ---------------------------------------------------------------------------
__global__ __launch_bounds__(256) void ln_kernel(
    float* AO,                     // aliased read A / write out — no restrict
    const float* __restrict__ x,
    const float* __restrict__ gamma, const float* __restrict__ beta)
{
    const int lane = threadIdx.x & 63;
    const int wid  = threadIdx.x >> 6;
    const size_t row = (size_t)blockIdx.x * 4 + wid;

    const float4 a  = ((const float4*)(AO + row * D_MODEL))[lane];
    const float4 xv = ((const float4*)(x + row * D_MODEL))[lane];
    float hv[4];
    hv[0] = a.x + xv.x;
    hv[1] = a.y + xv.y;
    hv[2] = a.z + xv.z;
    hv[3] = a.w + xv.w;

    float s = hv[0] + hv[1] + hv[2] + hv[3];
    #pragma unroll
    for (int off = 32; off > 0; off >>= 1) s += __shfl_xor(s, off, 64);
    const float mu = s * (1.0f / D_MODEL);

    float d0 = hv[0]-mu, d1 = hv[1]-mu, d2 = hv[2]-mu, d3 = hv[3]-mu;
    float ss = d0*d0 + d1*d1 + d2*d2 + d3*d3;
    #pragma unroll
    for (int off = 32; off > 0; off >>= 1) ss += __shfl_xor(ss, off, 64);
    const float rs = rsqrtf(ss * (1.0f / D_MODEL) + LN_EPS);

    const float4 g  = ((const float4*)gamma)[lane];
    const float4 bb = ((const float4*)beta)[lane];
    float4 y;
    y.x = g.x * d0 * rs + bb.x;
    y.y = g.y * d1 * rs + bb.y;
    y.z = g.z * d2 * rs + bb.z;
    y.w = g.w * d3 * rs + bb.w;
    ((float4*)(AO + row * D_MODEL))[lane] = y;
}

// ---------------------------------------------------------------------------
extern "C" void kernel_launch(void* const* d_in, const int* in_sizes, int n_in,
                              void* d_out, int out_size, void* d_ws, size_t ws_size,
                              hipStream_t stream)
{
    const float* x     = (const float*)d_in[0];
    const float* pad   = (const float*)d_in[1];
    const float* Wq    = (const float*)d_in[2];
    const float* bq    = (const float*)d_in[3];
    const float* Wk    = (const float*)d_in[4];
    const float* bk    = (const float*)d_in[5];
    const float* Wv    = (const float*)d_in[6];
    const float* bv    = (const float*)d_in[7];
    const float* gamma = (const float*)d_in[8];
    const float* beta  = (const float*)d_in[9];

    const size_t elems = (size_t)NROWS * D_MODEL;       // 2M
    unsigned short* Qh = (unsigned short*)d_ws;          // 4 MB
    unsigned short* Kh = Qh + elems;                     // 4 MB
    unsigned short* Vt = Kh + elems;                     // 4 MB
    float* T2 = (float*)(Vt + elems);                    // 32 KB
    unsigned short* Wt = (unsigned short*)(T2 + NROWS);  // 768x256 bf16, 384 KB
    float* biasc = (float*)(Wt + 768 * 256);             // 3 KB
    float* AO = (float*)d_out;                           // attn out + final out

    prep_kernel<<<800, 256, 0, stream>>>(Wq, Wk, Wv, bq, bk, bv, pad,
                                         Wt, biasc, T2);
    qkv_mfma_kernel<<<(NROWS / 64) * 8, 256, 0, stream>>>(x, Wt, biasc,
                                                          Qh, Kh, Vt);
    attn_mfma_kernel<<<BATCH * NUM_HEADS * (SEQ / 128), 512, 0, stream>>>(
        Qh, Kh, Vt, T2, AO);
    ln_kernel<<<NROWS / 4, 256, 0, stream>>>(AO, x, gamma, beta);
}

// Round 7
// 171.812 us; speedup vs baseline: 1.0232x; 1.0232x over previous
//
#include <hip/hip_runtime.h>
#include <hip/hip_bf16.h>

#define D_MODEL 256
#define NUM_HEADS 8
#define DIM_HEAD 32
#define SEQ 4096
#define BATCH 2
#define NROWS (BATCH * SEQ)              // 8192
#define LN_EPS 1e-6f
#define MASK_BIAS -1.0e9f
#define SCALE 0.17677669529663687f      // 1/sqrt(32)
#define LOG2E 1.4426950408889634f
#define QSCALE (SCALE * LOG2E)          // folded into Q at projection time

typedef __attribute__((ext_vector_type(8))) short short8;   // 8 bf16 (4 VGPRs)
typedef __attribute__((ext_vector_type(4))) float f32x4;    // MFMA C/D

// fp32 -> bf16 bits (RNE)
static __device__ __forceinline__ unsigned short f2b(float f) {
    union { __hip_bfloat16 b; unsigned short u; } cv;
    cv.b = __float2bfloat16(f);
    return cv.u;
}
// packed fp32 pair -> bf16x2 (RNE), lo in low 16 bits
static __device__ __forceinline__ unsigned int pk_bf16(float lo, float hi) {
    union { __hip_bfloat162 v; unsigned int u; } cv;
    cv.v = __float22bfloat162_rn(make_float2(lo, hi));
    return cv.u;
}
// raw v_exp_f32: 1 instruction (no libm fixup)
static __device__ __forceinline__ float exp2_raw(float x) {
#if __has_builtin(__builtin_amdgcn_exp2f)
    return __builtin_amdgcn_exp2f(x);
#else
    float r;
    asm volatile("v_exp_f32 %0, %1" : "=v"(r) : "v"(x));
    return r;
#endif
}
// async global->LDS, 16B per lane; LDS dest = uniform base + lane*16
static __device__ __forceinline__ void load_lds16(const void* g, void* l) {
    __builtin_amdgcn_global_load_lds(
        (const __attribute__((address_space(1))) unsigned int*)g,
        (__attribute__((address_space(3))) unsigned int*)l, 16, 0, 0);
}

// ---------------------------------------------------------------------------
// Kernel 0: prep (R19 rewrite — no scattered 2B writes).
// Blocks 0..47: Wt[n_cat][k0..k0+15] — each thread gathers 16 fp32 from a
// W column (coalesced across lanes), packs to bf16, writes 2x16B contiguous.
// Blocks 48..79: T2 = pad * (-1e9*scale*log2e).
// ---------------------------------------------------------------------------
__global__ __launch_bounds__(256) void prep_kernel(
    const float* __restrict__ Wq, const float* __restrict__ Wk,
    const float* __restrict__ Wv,
    const float* __restrict__ bq, const float* __restrict__ bk,
    const float* __restrict__ bv,
    const float* __restrict__ pad,
    unsigned short* __restrict__ Wt, float* __restrict__ biasc,
    float* __restrict__ T2)
{
    const int blk = blockIdx.x;
    const int t = threadIdx.x;
    if (blk < 48) {
        const int w = blk >> 4;            // 0=Q 1=K 2=V
        const int k0 = (blk & 15) * 16;    // k-chunk base
        const float* W = (w == 0) ? Wq : (w == 1) ? Wk : Wv;
        float v[16];
        #pragma unroll
        for (int k = 0; k < 16; k++)
            v[k] = W[(size_t)(k0 + k) * 256 + t];   // coalesced across lanes
        unsigned int u[8];
        #pragma unroll
        for (int i = 0; i < 8; i++)
            u[i] = pk_bf16(v[2 * i], v[2 * i + 1]);
        unsigned short* dst = Wt + (size_t)(w * 256 + t) * 256 + k0;
        *(uint4*)(dst)     = make_uint4(u[0], u[1], u[2], u[3]);
        *(uint4*)(dst + 8) = make_uint4(u[4], u[5], u[6], u[7]);
        if ((blk & 15) == 0) {
            const float* bb = (w == 0) ? bq : (w == 1) ? bk : bv;
            biasc[w * 256 + t] = bb[t];
        }
    } else {
        const int i = (blk - 48) * 256 + t;
        T2[i] = pad[i] * (MASK_BIAS * SCALE * LOG2E);
    }
}

// ---------------------------------------------------------------------------
// Kernel 1: QKV projection as bf16 MFMA GEMM.
// R19 change: Q/K epilogue goes through a wave-local LDS transpose so the
// global stores are 8B-packed / 32B-contiguous (old path: 2B stores at 64B
// stride = 64 cache lines per wave-store). V keeps its already-packed direct
// path. Bank math: LW stride 102 floats -> writes <=2-way (free), float2
// reads 8B-aligned and <=2-way. Math bit-identical (same RNE, same order).
// ---------------------------------------------------------------------------
__global__ __launch_bounds__(256) void qkv_mfma_kernel(
    const float* __restrict__ x, const unsigned short* __restrict__ Wt,
    const float* __restrict__ biasc,
    unsigned short* __restrict__ Qh, unsigned short* __restrict__ Kh,
    unsigned short* __restrict__ Vt)
{
    __shared__ float LW[4][16][102];       // per-wave transpose scratch, 26.1KB

    const int lane = threadIdx.x & 63;
    const int wid  = threadIdx.x >> 6;
    const int c    = lane & 15;
    const int quad = lane >> 4;

    const int r0 = (blockIdx.x >> 3) * 64 + wid * 16;   // wave row base
    const int n0 = (blockIdx.x & 7) * 96;               // wave col base

    f32x4 acc[6];
    float bias[6];
    #pragma unroll
    for (int t = 0; t < 6; t++) {
        acc[t] = (f32x4){0.f, 0.f, 0.f, 0.f};
        bias[t] = biasc[n0 + 16 * t + c];
    }

    const float* xp0 = x + (size_t)(r0 + c) * D_MODEL + quad * 8;
    const unsigned short* wp0 = Wt + (size_t)(n0 + c) * 256 + quad * 8;

    for (int k0 = 0; k0 < 256; k0 += 32) {
        const float4 a0 = *(const float4*)(xp0 + k0);
        const float4 a1 = *(const float4*)(xp0 + k0 + 4);
        union { unsigned int u[4]; short8 s; } af;
        af.u[0] = pk_bf16(a0.x, a0.y);
        af.u[1] = pk_bf16(a0.z, a0.w);
        af.u[2] = pk_bf16(a1.x, a1.y);
        af.u[3] = pk_bf16(a1.z, a1.w);
        #pragma unroll
        for (int t = 0; t < 6; t++) {
            const short8 bf = *(const short8*)(wp0 + (size_t)(16 * t) * 256 + k0);
            acc[t] = __builtin_amdgcn_mfma_f32_16x16x32_bf16(af.s, bf, acc[t], 0, 0, 0);
        }
    }

    float* lw = &LW[wid][0][0];
    #pragma unroll
    for (int t = 0; t < 6; t++) {
        const int col = n0 + 16 * t;          // tile col base (multiple of 16)
        const int mm  = col >> 8;             // 0=Q 1=K 2=V (uniform per tile)
        float v0 = acc[t][0] + bias[t];
        float v1 = acc[t][1] + bias[t];
        float v2 = acc[t][2] + bias[t];
        float v3 = acc[t][3] + bias[t];
        if (mm == 2) {
            const int dim = (col & 255) + c;
            const int h = dim >> 5, d = dim & 31;
            const int row = r0 + quad * 4;
            const int bb = row >> 12;
            const int s  = row & (SEQ - 1);
            const size_t bh = (size_t)(bb * NUM_HEADS + h);
            uint2 pk = make_uint2(pk_bf16(v0, v1), pk_bf16(v2, v3));
            *(uint2*)(Vt + (bh * DIM_HEAD + d) * SEQ + s) = pk;
        } else {
            if (mm == 0) {                    // pre-scale Q by SCALE*LOG2E
                v0 *= QSCALE; v1 *= QSCALE; v2 *= QSCALE; v3 *= QSCALE;
            }
            const int e = 16 * t + c;
            lw[(quad * 4 + 0) * 102 + e] = v0;
            lw[(quad * 4 + 1) * 102 + e] = v1;
            lw[(quad * 4 + 2) * 102 + e] = v2;
            lw[(quad * 4 + 3) * 102 + e] = v3;
        }
    }

    // readback: per 32-col head group, emit 8B-packed stores (32B contiguous
    // per row per instruction). Wave-local LDS; compiler inserts lgkmcnt.
    #pragma unroll
    for (int hg = 0; hg < 3; hg++) {
        const int col32 = n0 + 32 * hg;
        const int mm = col32 >> 8;
        if (mm == 2) continue;
        unsigned short* Pm = (mm == 0) ? Qh : Kh;
        const int h = (col32 & 255) >> 5;
        const int row = r0 + (lane & 15);
        const size_t bh = (size_t)((row >> 12) * NUM_HEADS + h);
        const int srow = row & (SEQ - 1);
        unsigned short* Pr = Pm + (bh * SEQ + srow) * DIM_HEAD;
        #pragma unroll
        for (int ii = 0; ii < 2; ii++) {
            const int cc = (lane >> 4) + 4 * ii;          // 0..7
            const int e = (lane & 15) * 102 + 32 * hg + cc * 4;
            const float2 lo = *(const float2*)&lw[e];
            const float2 hi = *(const float2*)&lw[e + 2];
            uint2 pk = make_uint2(pk_bf16(lo.x, lo.y), pk_bf16(hi.x, hi.y));
            *(uint2*)(Pr + cc * 4) = pk;
        }
    }
}

// ---------------------------------------------------------------------------
// Kernel 2: MFMA flash attention v10 (R17 best-measured config, restored).
// 128-key rounds, 8 waves (4 q-tiles x 2 key halves), triple-buffered
// counted-vmcnt staging (vmcnt(2)/vmcnt(3), never 0 in-loop), T in LDS,
// LDS combine for key-split halves. R18's T-in-regs + setprio was neutral-
// negative (70.5 vs 69.4) -> reverted.
// ---------------------------------------------------------------------------
__global__ __launch_bounds__(512, 4) void attn_mfma_kernel(
    const unsigned short* __restrict__ Qh, const unsigned short* __restrict__ Kh,
    const unsigned short* __restrict__ Vt, const float* __restrict__ T2,
    float* __restrict__ O)
{
    // layout (bytes): K 3x8KB @0, V 3x8KB @24576, T 3x512B @49152
    // combine scratch (20480B) overlays K region after the loop drains.
    __shared__ __align__(16) unsigned char smem[50688];
    unsigned short* smem_s = (unsigned short*)smem;
    float* Tf = (float*)(smem + 49152);

    const int lane = threadIdx.x & 63;
    const int wid  = threadIdx.x >> 6;     // 0..7
    const int cwid = wid & 3;              // query-tile id within block
    const int shalf = wid >> 2;            // which 64-key half this wave owns
    const int c    = lane & 15;
    const int quad = lane >> 4;

    const int gw = blockIdx.x;                   // 0..511
    const int q0 = (gw & 31) * 128;              // 128 queries per block
    const int h  = (gw >> 5) & (NUM_HEADS - 1);
    const int b  = gw >> 8;
    const size_t bh = (size_t)(b * NUM_HEADS + h);

    const int perm = ((c & 12) << 1) | (c & 3);  // pi(c)

    const unsigned short* Kb = Kh + bh * SEQ * DIM_HEAD;
    const unsigned short* Vb = Vt + bh * DIM_HEAD * SEQ;
    const float* Tb = T2 + (size_t)b * SEQ;

    // wave's 32 queries: q0 + cwid*32 + {c, 16+c}  (shared with wave cwid+4)
    const int qrow = q0 + cwid * 32;
    const short8 qfA = *(const short8*)(Qh + (bh * SEQ + qrow + c) * DIM_HEAD + quad * 8);
    const short8 qfB = *(const short8*)(Qh + (bh * SEQ + qrow + 16 + c) * DIM_HEAD + quad * 8);

    union { unsigned int u[4]; short8 s; } ones;
    ones.u[0] = ones.u[1] = ones.u[2] = ones.u[3] = 0x3F803F80u;  // bf16 1.0 x2

    // loop-invariant LDS read offsets (elements). f(key)=((key>>1)^(key>>3))&3
    // is invariant to key += 32, so kA/kB generalize to sub s via +s*1024.
    // V key-group swizzle: address = vbase ^ (s<<5).
    const int f0 = ((perm >> 1) ^ (perm >> 3)) & 3;
    const int f1 = (((perm + 4) >> 1) ^ ((perm + 4) >> 3)) & 3;
    const int kA = perm * 32 + ((quad ^ f0) << 3);        // + s*1024
    const int kB = (perm + 4) * 32 + ((quad ^ f1) << 3);
    const int g0 = quad ^ (c & 7);
    const int vbase0 = c * 128 + (g0 << 3);               // ^ (s<<5)
    const int vbase1 = (16 + c) * 128 + (g0 << 3);        // (16+c)&7 == c&7

    // staging lane constants
    const int skey = (lane >> 2);                // K: + j*16
    const int sgK  = lane & 3;
    const int sdim = lane >> 4;                  // V: + j*4
    const int sgV  = lane & 15;

    f32x4 oA0 = {0.f,0.f,0.f,0.f}, oA1 = {0.f,0.f,0.f,0.f};
    f32x4 oB0 = {0.f,0.f,0.f,0.f}, oB1 = {0.f,0.f,0.f,0.f};
    f32x4 laccA = {0.f,0.f,0.f,0.f}, laccB = {0.f,0.f,0.f,0.f};

    // stage 128-key chunk ch into buffer pb.
    // waves 0-3: K tiles j=wid*2+jj (16 keys each, 2 loads);
    // waves 4-7: V tiles j=(wid-4)*2+jj (4 dims each, 2 loads); wave 7 +T.
    auto stage = [&](int ch, int pb) {
        const int s0 = ch * 128;
        if (wid < 4) {
            #pragma unroll
            for (int jj = 0; jj < 2; jj++) {
                const int j = wid * 2 + jj;
                const int key = j * 16 + skey;
                const int f = ((key >> 1) ^ (key >> 3)) & 3;
                load_lds16(Kb + (size_t)(s0 + key) * 32 + ((sgK ^ f) << 3),
                           &smem_s[pb * 4096 + j * 512]);
            }
        } else {
            #pragma unroll
            for (int jj = 0; jj < 2; jj++) {
                const int j = (wid - 4) * 2 + jj;
                const int dim = j * 4 + sdim;
                load_lds16(Vb + (size_t)dim * SEQ + s0 + ((sgV ^ (dim & 7)) << 3),
                           &smem_s[12288 + pb * 4096 + j * 512]);
            }
            if (wid == 7 && lane < 32)
                load_lds16(Tb + s0 + lane * 4, Tf + pb * 128);
        }
    };

    // one 32-key sub-chunk s (0..3) from buffer pb; T folded in as MFMA C.
    auto sub = [&](int pb, int s) {
        const short8 kf0 = *(const short8*)&smem_s[pb * 4096 + s * 1024 + kA];
        const short8 kf1 = *(const short8*)&smem_s[pb * 4096 + s * 1024 + kB];
        const short8 vf0 = *(const short8*)&smem_s[12288 + pb * 4096 + (vbase0 ^ (s << 5))];
        const short8 vf1 = *(const short8*)&smem_s[12288 + pb * 4096 + (vbase1 ^ (s << 5))];
        const f32x4 c0 = *(const f32x4*)&Tf[pb * 128 + s * 32 + quad * 8];
        const f32x4 c1 = *(const f32x4*)&Tf[pb * 128 + s * 32 + quad * 8 + 4];

        const f32x4 sA0 = __builtin_amdgcn_mfma_f32_16x16x32_bf16(kf0, qfA, c0, 0, 0, 0);
        const f32x4 sA1 = __builtin_amdgcn_mfma_f32_16x16x32_bf16(kf1, qfA, c1, 0, 0, 0);
        const f32x4 sB0 = __builtin_amdgcn_mfma_f32_16x16x32_bf16(kf0, qfB, c0, 0, 0, 0);
        const f32x4 sB1 = __builtin_amdgcn_mfma_f32_16x16x32_bf16(kf1, qfB, c1, 0, 0, 0);

        union { unsigned int u[4]; short8 s8; } pfA, pfB;
        {
            float p0 = exp2_raw(sA0[0]), p1 = exp2_raw(sA0[1]);
            float p2 = exp2_raw(sA0[2]), p3 = exp2_raw(sA0[3]);
            float p4 = exp2_raw(sA1[0]), p5 = exp2_raw(sA1[1]);
            float p6 = exp2_raw(sA1[2]), p7 = exp2_raw(sA1[3]);
            pfA.u[0] = pk_bf16(p0, p1);
            pfA.u[1] = pk_bf16(p2, p3);
            pfA.u[2] = pk_bf16(p4, p5);
            pfA.u[3] = pk_bf16(p6, p7);
        }
        {
            float p0 = exp2_raw(sB0[0]), p1 = exp2_raw(sB0[1]);
            float p2 = exp2_raw(sB0[2]), p3 = exp2_raw(sB0[3]);
            float p4 = exp2_raw(sB1[0]), p5 = exp2_raw(sB1[1]);
            float p6 = exp2_raw(sB1[2]), p7 = exp2_raw(sB1[3]);
            pfB.u[0] = pk_bf16(p0, p1);
            pfB.u[1] = pk_bf16(p2, p3);
            pfB.u[2] = pk_bf16(p4, p5);
            pfB.u[3] = pk_bf16(p6, p7);
        }

        laccA = __builtin_amdgcn_mfma_f32_16x16x32_bf16(ones.s, pfA.s8, laccA, 0, 0, 0);
        laccB = __builtin_amdgcn_mfma_f32_16x16x32_bf16(ones.s, pfB.s8, laccB, 0, 0, 0);
        oA0   = __builtin_amdgcn_mfma_f32_16x16x32_bf16(vf0,   pfA.s8, oA0,   0, 0, 0);
        oA1   = __builtin_amdgcn_mfma_f32_16x16x32_bf16(vf1,   pfA.s8, oA1,   0, 0, 0);
        oB0   = __builtin_amdgcn_mfma_f32_16x16x32_bf16(vf0,   pfB.s8, oB0,   0, 0, 0);
        oB1   = __builtin_amdgcn_mfma_f32_16x16x32_bf16(vf1,   pfB.s8, oB1,   0, 0, 0);
    };

    // prologue: prefetch chunks 0 and 1
    stage(0, 0);
    stage(1, 1);

    int rb = 0;          // read buffer  = ch % 3
    int sb = 2;          // stage buffer = (ch+2) % 3
    for (int ch = 0; ch < SEQ / 128; ++ch) {
        // wait for MY stage(ch) loads (the newer stage(ch+1)'s 2-3 ops stay
        // in flight); lgkmcnt(0): my LDS reads of buf[(ch-1)%3] are done.
        if (wid == 7)
            asm volatile("s_waitcnt vmcnt(3) lgkmcnt(0)" ::: "memory");
        else
            asm volatile("s_waitcnt vmcnt(2) lgkmcnt(0)" ::: "memory");
        __builtin_amdgcn_s_barrier();
        __builtin_amdgcn_sched_barrier(0);
        stage((ch + 2) & 31, sb);        // overwrite buf[(ch-1)%3]
        sub(rb, shalf * 2);              // this wave's two 32-key subs
        sub(rb, shalf * 2 + 1);
        rb = (rb == 2) ? 0 : rb + 1;
        sb = (sb == 2) ? 0 : sb + 1;
    }

    // drain ALL in-flight staging (wrap prefetches included) before reusing
    // the K LDS region as combine scratch.
    asm volatile("s_waitcnt vmcnt(0) lgkmcnt(0)" ::: "memory");
    __builtin_amdgcn_s_barrier();

    float* CS = (float*)smem;            // 256 slots x 20 floats = 20480 B
    if (wid >= 4) {
        const int slot = ((cwid * 64) + lane) * 20;
        *(f32x4*)&CS[slot + 0]  = oA0;
        *(f32x4*)&CS[slot + 4]  = oA1;
        *(f32x4*)&CS[slot + 8]  = oB0;
        *(f32x4*)&CS[slot + 12] = oB1;
        CS[slot + 16] = laccA[0];
        CS[slot + 17] = laccB[0];
    }
    asm volatile("s_waitcnt lgkmcnt(0)" ::: "memory");
    __builtin_amdgcn_s_barrier();
    if (wid < 4) {
        const int slot = ((cwid * 64) + lane) * 20;
        const f32x4 pA0 = *(const f32x4*)&CS[slot + 0];
        const f32x4 pA1 = *(const f32x4*)&CS[slot + 4];
        const f32x4 pB0 = *(const f32x4*)&CS[slot + 8];
        const f32x4 pB1 = *(const f32x4*)&CS[slot + 12];
        const float invA = 1.0f / (laccA[0] + CS[slot + 16]);
        const float invB = 1.0f / (laccB[0] + CS[slot + 17]);
        oA0 += pA0; oA1 += pA1; oB0 += pB0; oB1 += pB1;

        float* opA = O + ((size_t)(b * SEQ) + qrow + c) * D_MODEL + h * DIM_HEAD + quad * 4;
        float* opB = O + ((size_t)(b * SEQ) + qrow + 16 + c) * D_MODEL + h * DIM_HEAD + quad * 4;
        *(float4*)opA        = make_float4(oA0[0]*invA, oA0[1]*invA, oA0[2]*invA, oA0[3]*invA);
        *(float4*)(opA + 16) = make_float4(oA1[0]*invA, oA1[1]*invA, oA1[2]*invA, oA1[3]*invA);
        *(float4*)opB        = make_float4(oB0[0]*invB, oB0[1]*invB, oB0[2]*invB, oB0[3]*invB);
        *(float4*)(opB + 16) = make_float4(oB1[0]*invB, oB1[1]*invB, oB1[2]*invB, oB1[3]*invB);
    }
}

// ---------------------------------------------------------------------------
// Kernel 3: residual add + LayerNorm IN PLACE on d_out (fp32 -> fp32).
// ---------------------------------------------------------------------------
__global__ __launch_bounds__(256) void ln_kernel(
    float* AO,                     // aliased read A / write out — no restrict
    const float* __restrict__ x,
    const float* __restrict__ gamma, const float* __restrict__ beta)
{
    const int lane = threadIdx.x & 63;
    const int wid  = threadIdx.x >> 6;
    const size_t row = (size_t)blockIdx.x * 4 + wid;

    const float4 a  = ((const float4*)(AO + row * D_MODEL))[lane];
    const float4 xv = ((const float4*)(x + row * D_MODEL))[lane];
    float hv[4];
    hv[0] = a.x + xv.x;
    hv[1] = a.y + xv.y;
    hv[2] = a.z + xv.z;
    hv[3] = a.w + xv.w;

    float s = hv[0] + hv[1] + hv[2] + hv[3];
    #pragma unroll
    for (int off = 32; off > 0; off >>= 1) s += __shfl_xor(s, off, 64);
    const float mu = s * (1.0f / D_MODEL);

    float d0 = hv[0]-mu, d1 = hv[1]-mu, d2 = hv[2]-mu, d3 = hv[3]-mu;
    float ss = d0*d0 + d1*d1 + d2*d2 + d3*d3;
    #pragma unroll
    for (int off = 32; off > 0; off >>= 1) ss += __shfl_xor(ss, off, 64);
    const float rs = rsqrtf(ss * (1.0f / D_MODEL) + LN_EPS);

    const float4 g  = ((const float4*)gamma)[lane];
    const float4 bb = ((const float4*)beta)[lane];
    float4 y;
    y.x = g.x * d0 * rs + bb.x;
    y.y = g.y * d1 * rs + bb.y;
    y.z = g.z * d2 * rs + bb.z;
    y.w = g.w * d3 * rs + bb.w;
    ((float4*)(AO + row * D_MODEL))[lane] = y;
}

// ---------------------------------------------------------------------------
extern "C" void kernel_launch(void* const* d_in, const int* in_sizes, int n_in,
                              void* d_out, int out_size, void* d_ws, size_t ws_size,
                              hipStream_t stream)
{
    const float* x     = (const float*)d_in[0];
    const float* pad   = (const float*)d_in[1];
    const float* Wq    = (const float*)d_in[2];
    const float* bq    = (const float*)d_in[3];
    const float* Wk    = (const float*)d_in[4];
    const float* bk    = (const float*)d_in[5];
    const float* Wv    = (const float*)d_in[6];
    const float* bv    = (const float*)d_in[7];
    const float* gamma = (const float*)d_in[8];
    const float* beta  = (const float*)d_in[9];

    const size_t elems = (size_t)NROWS * D_MODEL;       // 2M
    unsigned short* Qh = (unsigned short*)d_ws;          // 4 MB
    unsigned short* Kh = Qh + elems;                     // 4 MB
    unsigned short* Vt = Kh + elems;                     // 4 MB
    float* T2 = (float*)(Vt + elems);                    // 32 KB
    unsigned short* Wt = (unsigned short*)(T2 + NROWS);  // 768x256 bf16, 384 KB
    float* biasc = (float*)(Wt + 768 * 256);             // 3 KB
    float* AO = (float*)d_out;                           // attn out + final out

    prep_kernel<<<80, 256, 0, stream>>>(Wq, Wk, Wv, bq, bk, bv, pad,
                                        Wt, biasc, T2);
    qkv_mfma_kernel<<<(NROWS / 64) * 8, 256, 0, stream>>>(x, Wt, biasc,
                                                          Qh, Kh, Vt);
    attn_mfma_kernel<<<BATCH * NUM_HEADS * (SEQ / 128), 512, 0, stream>>>(
        Qh, Kh, Vt, T2, AO);
    ln_kernel<<<NROWS / 4, 256, 0, stream>>>(AO, x, gamma, beta);
}

// Round 8
// 171.174 us; speedup vs baseline: 1.0270x; 1.0037x over previous
//
#include <hip/hip_runtime.h>
#include <hip/hip_bf16.h>

#define D_MODEL 256
#define NUM_HEADS 8
#define DIM_HEAD 32
#define SEQ 4096
#define BATCH 2
#define NROWS (BATCH * SEQ)              // 8192
#define LN_EPS 1e-6f
#define MASK_BIAS -1.0e9f
#define SCALE 0.17677669529663687f      // 1/sqrt(32)
#define LOG2E 1.4426950408889634f
#define QSCALE (SCALE * LOG2E)          // folded into Q at projection time

typedef __attribute__((ext_vector_type(8))) short short8;   // 8 bf16 (4 VGPRs)
typedef __attribute__((ext_vector_type(4))) float f32x4;    // MFMA C/D

// fp32 -> bf16 bits (RNE)
static __device__ __forceinline__ unsigned short f2b(float f) {
    union { __hip_bfloat16 b; unsigned short u; } cv;
    cv.b = __float2bfloat16(f);
    return cv.u;
}
// packed fp32 pair -> bf16x2 (RNE), lo in low 16 bits
static __device__ __forceinline__ unsigned int pk_bf16(float lo, float hi) {
    union { __hip_bfloat162 v; unsigned int u; } cv;
    cv.v = __float22bfloat162_rn(make_float2(lo, hi));
    return cv.u;
}
// raw v_exp_f32: 1 instruction (no libm fixup)
static __device__ __forceinline__ float exp2_raw(float x) {
#if __has_builtin(__builtin_amdgcn_exp2f)
    return __builtin_amdgcn_exp2f(x);
#else
    float r;
    asm volatile("v_exp_f32 %0, %1" : "=v"(r) : "v"(x));
    return r;
#endif
}
// async global->LDS, 16B per lane; LDS dest = uniform base + lane*16
static __device__ __forceinline__ void load_lds16(const void* g, void* l) {
    __builtin_amdgcn_global_load_lds(
        (const __attribute__((address_space(1))) unsigned int*)g,
        (__attribute__((address_space(3))) unsigned int*)l, 16, 0, 0);
}

// ---------------------------------------------------------------------------
// Kernel 0: prep (no scattered 2B writes).
// Blocks 0..47: Wt[n_cat][k0..k0+15] — each thread gathers 16 fp32 from a
// W column (coalesced across lanes), packs to bf16, writes 2x16B contiguous.
// Blocks 48..79: T2 = pad * (-1e9*scale*log2e).
// ---------------------------------------------------------------------------
__global__ __launch_bounds__(256) void prep_kernel(
    const float* __restrict__ Wq, const float* __restrict__ Wk,
    const float* __restrict__ Wv,
    const float* __restrict__ bq, const float* __restrict__ bk,
    const float* __restrict__ bv,
    const float* __restrict__ pad,
    unsigned short* __restrict__ Wt, float* __restrict__ biasc,
    float* __restrict__ T2)
{
    const int blk = blockIdx.x;
    const int t = threadIdx.x;
    if (blk < 48) {
        const int w = blk >> 4;            // 0=Q 1=K 2=V
        const int k0 = (blk & 15) * 16;    // k-chunk base
        const float* W = (w == 0) ? Wq : (w == 1) ? Wk : Wv;
        float v[16];
        #pragma unroll
        for (int k = 0; k < 16; k++)
            v[k] = W[(size_t)(k0 + k) * 256 + t];   // coalesced across lanes
        unsigned int u[8];
        #pragma unroll
        for (int i = 0; i < 8; i++)
            u[i] = pk_bf16(v[2 * i], v[2 * i + 1]);
        unsigned short* dst = Wt + (size_t)(w * 256 + t) * 256 + k0;
        *(uint4*)(dst)     = make_uint4(u[0], u[1], u[2], u[3]);
        *(uint4*)(dst + 8) = make_uint4(u[4], u[5], u[6], u[7]);
        if ((blk & 15) == 0) {
            const float* bb = (w == 0) ? bq : (w == 1) ? bk : bv;
            biasc[w * 256 + t] = bb[t];
        }
    } else {
        const int i = (blk - 48) * 256 + t;
        T2[i] = pad[i] * (MASK_BIAS * SCALE * LOG2E);
    }
}

// ---------------------------------------------------------------------------
// Kernel 1: QKV projection as bf16 MFMA GEMM. Q pre-scaled by QSCALE.
// Q/K epilogue via wave-local LDS transpose -> 8B-packed 32B-contiguous
// stores; V direct packed path.
// ---------------------------------------------------------------------------
__global__ __launch_bounds__(256) void qkv_mfma_kernel(
    const float* __restrict__ x, const unsigned short* __restrict__ Wt,
    const float* __restrict__ biasc,
    unsigned short* __restrict__ Qh, unsigned short* __restrict__ Kh,
    unsigned short* __restrict__ Vt)
{
    __shared__ float LW[4][16][102];       // per-wave transpose scratch, 26.1KB

    const int lane = threadIdx.x & 63;
    const int wid  = threadIdx.x >> 6;
    const int c    = lane & 15;
    const int quad = lane >> 4;

    const int r0 = (blockIdx.x >> 3) * 64 + wid * 16;   // wave row base
    const int n0 = (blockIdx.x & 7) * 96;               // wave col base

    f32x4 acc[6];
    float bias[6];
    #pragma unroll
    for (int t = 0; t < 6; t++) {
        acc[t] = (f32x4){0.f, 0.f, 0.f, 0.f};
        bias[t] = biasc[n0 + 16 * t + c];
    }

    const float* xp0 = x + (size_t)(r0 + c) * D_MODEL + quad * 8;
    const unsigned short* wp0 = Wt + (size_t)(n0 + c) * 256 + quad * 8;

    for (int k0 = 0; k0 < 256; k0 += 32) {
        const float4 a0 = *(const float4*)(xp0 + k0);
        const float4 a1 = *(const float4*)(xp0 + k0 + 4);
        union { unsigned int u[4]; short8 s; } af;
        af.u[0] = pk_bf16(a0.x, a0.y);
        af.u[1] = pk_bf16(a0.z, a0.w);
        af.u[2] = pk_bf16(a1.x, a1.y);
        af.u[3] = pk_bf16(a1.z, a1.w);
        #pragma unroll
        for (int t = 0; t < 6; t++) {
            const short8 bf = *(const short8*)(wp0 + (size_t)(16 * t) * 256 + k0);
            acc[t] = __builtin_amdgcn_mfma_f32_16x16x32_bf16(af.s, bf, acc[t], 0, 0, 0);
        }
    }

    float* lw = &LW[wid][0][0];
    #pragma unroll
    for (int t = 0; t < 6; t++) {
        const int col = n0 + 16 * t;          // tile col base (multiple of 16)
        const int mm  = col >> 8;             // 0=Q 1=K 2=V (uniform per tile)
        float v0 = acc[t][0] + bias[t];
        float v1 = acc[t][1] + bias[t];
        float v2 = acc[t][2] + bias[t];
        float v3 = acc[t][3] + bias[t];
        if (mm == 2) {
            const int dim = (col & 255) + c;
            const int h = dim >> 5, d = dim & 31;
            const int row = r0 + quad * 4;
            const int bb = row >> 12;
            const int s  = row & (SEQ - 1);
            const size_t bh = (size_t)(bb * NUM_HEADS + h);
            uint2 pk = make_uint2(pk_bf16(v0, v1), pk_bf16(v2, v3));
            *(uint2*)(Vt + (bh * DIM_HEAD + d) * SEQ + s) = pk;
        } else {
            if (mm == 0) {                    // pre-scale Q by SCALE*LOG2E
                v0 *= QSCALE; v1 *= QSCALE; v2 *= QSCALE; v3 *= QSCALE;
            }
            const int e = 16 * t + c;
            lw[(quad * 4 + 0) * 102 + e] = v0;
            lw[(quad * 4 + 1) * 102 + e] = v1;
            lw[(quad * 4 + 2) * 102 + e] = v2;
            lw[(quad * 4 + 3) * 102 + e] = v3;
        }
    }

    // readback: per 32-col head group, emit 8B-packed stores (32B contiguous
    // per row per instruction). Wave-local LDS; compiler inserts lgkmcnt.
    #pragma unroll
    for (int hg = 0; hg < 3; hg++) {
        const int col32 = n0 + 32 * hg;
        const int mm = col32 >> 8;
        if (mm == 2) continue;
        unsigned short* Pm = (mm == 0) ? Qh : Kh;
        const int h = (col32 & 255) >> 5;
        const int row = r0 + (lane & 15);
        const size_t bh = (size_t)((row >> 12) * NUM_HEADS + h);
        const int srow = row & (SEQ - 1);
        unsigned short* Pr = Pm + (bh * SEQ + srow) * DIM_HEAD;
        #pragma unroll
        for (int ii = 0; ii < 2; ii++) {
            const int cc = (lane >> 4) + 4 * ii;          // 0..7
            const int e = (lane & 15) * 102 + 32 * hg + cc * 4;
            const float2 lo = *(const float2*)&lw[e];
            const float2 hi = *(const float2*)&lw[e + 2];
            uint2 pk = make_uint2(pk_bf16(lo.x, lo.y), pk_bf16(hi.x, hi.y));
            *(uint2*)(Pr + cc * 4) = pk;
        }
    }
}

// ---------------------------------------------------------------------------
// Kernel 2: MFMA flash attention v12 — DEFERRED PV (T15 att[2] pipeline).
// R20 change: round r's 12 PV/lacc MFMAs consume only registers (packed P +
// V fragments), so they are DEFERRED to the top of round r+1 — executed right
// after the barrier, covering stage-issue + ds_read latency of round r+1
// instead of serializing behind round r's exp burst. Carry = 8 short8
// (32 VGPR; VGPR 48->~84, cap 128). Everything else per R17 best-measured:
// 128-key rounds, 8 waves (4 q-tiles x 2 key halves), triple-buffered
// counted-vmcnt staging (vmcnt(2)/vmcnt(3), never 0 in-loop), T in LDS,
// LDS combine for key-split halves.
// Correctness: carry regs are produced from ds_reads pinned by lgkmcnt(0)
// before the barrier; PV-consumes-then-subQK-overwrites is a plain WAR the
// register allocator handles; buffer-reuse and vmcnt logic unchanged.
// ---------------------------------------------------------------------------
__global__ __launch_bounds__(512, 4) void attn_mfma_kernel(
    const unsigned short* __restrict__ Qh, const unsigned short* __restrict__ Kh,
    const unsigned short* __restrict__ Vt, const float* __restrict__ T2,
    float* __restrict__ O)
{
    // layout (bytes): K 3x8KB @0, V 3x8KB @24576, T 3x512B @49152
    // combine scratch (20480B) overlays K region after the loop drains.
    __shared__ __align__(16) unsigned char smem[50688];
    unsigned short* smem_s = (unsigned short*)smem;
    float* Tf = (float*)(smem + 49152);

    const int lane = threadIdx.x & 63;
    const int wid  = threadIdx.x >> 6;     // 0..7
    const int cwid = wid & 3;              // query-tile id within block
    const int shalf = wid >> 2;            // which 64-key half this wave owns
    const int c    = lane & 15;
    const int quad = lane >> 4;

    const int gw = blockIdx.x;                   // 0..511
    const int q0 = (gw & 31) * 128;              // 128 queries per block
    const int h  = (gw >> 5) & (NUM_HEADS - 1);
    const int b  = gw >> 8;
    const size_t bh = (size_t)(b * NUM_HEADS + h);

    const int perm = ((c & 12) << 1) | (c & 3);  // pi(c)

    const unsigned short* Kb = Kh + bh * SEQ * DIM_HEAD;
    const unsigned short* Vb = Vt + bh * DIM_HEAD * SEQ;
    const float* Tb = T2 + (size_t)b * SEQ;

    // wave's 32 queries: q0 + cwid*32 + {c, 16+c}  (shared with wave cwid+4)
    const int qrow = q0 + cwid * 32;
    const short8 qfA = *(const short8*)(Qh + (bh * SEQ + qrow + c) * DIM_HEAD + quad * 8);
    const short8 qfB = *(const short8*)(Qh + (bh * SEQ + qrow + 16 + c) * DIM_HEAD + quad * 8);

    union { unsigned int u[4]; short8 s; } ones;
    ones.u[0] = ones.u[1] = ones.u[2] = ones.u[3] = 0x3F803F80u;  // bf16 1.0 x2

    // loop-invariant LDS read offsets (elements). f(key)=((key>>1)^(key>>3))&3
    // is invariant to key += 32, so kA/kB generalize to sub s via +s*1024.
    // V key-group swizzle: address = vbase ^ (s<<5).
    const int f0 = ((perm >> 1) ^ (perm >> 3)) & 3;
    const int f1 = (((perm + 4) >> 1) ^ ((perm + 4) >> 3)) & 3;
    const int kA = perm * 32 + ((quad ^ f0) << 3);        // + s*1024
    const int kB = (perm + 4) * 32 + ((quad ^ f1) << 3);
    const int g0 = quad ^ (c & 7);
    const int vbase0 = c * 128 + (g0 << 3);               // ^ (s<<5)
    const int vbase1 = (16 + c) * 128 + (g0 << 3);        // (16+c)&7 == c&7

    // staging lane constants
    const int skey = (lane >> 2);                // K: + j*16
    const int sgK  = lane & 3;
    const int sdim = lane >> 4;                  // V: + j*4
    const int sgV  = lane & 15;

    f32x4 oA0 = {0.f,0.f,0.f,0.f}, oA1 = {0.f,0.f,0.f,0.f};
    f32x4 oB0 = {0.f,0.f,0.f,0.f}, oB1 = {0.f,0.f,0.f,0.f};
    f32x4 laccA = {0.f,0.f,0.f,0.f}, laccB = {0.f,0.f,0.f,0.f};

    // deferred-PV carry state (sub lo = this wave's first 32-key sub, hi = 2nd)
    short8 d_pfA0, d_pfB0, d_vf00, d_vf01;
    short8 d_pfA1, d_pfB1, d_vf10, d_vf11;

    // stage 128-key chunk ch into buffer pb.
    // waves 0-3: K tiles j=wid*2+jj (16 keys each, 2 loads);
    // waves 4-7: V tiles j=(wid-4)*2+jj (4 dims each, 2 loads); wave 7 +T.
    auto stage = [&](int ch, int pb) {
        const int s0 = ch * 128;
        if (wid < 4) {
            #pragma unroll
            for (int jj = 0; jj < 2; jj++) {
                const int j = wid * 2 + jj;
                const int key = j * 16 + skey;
                const int f = ((key >> 1) ^ (key >> 3)) & 3;
                load_lds16(Kb + (size_t)(s0 + key) * 32 + ((sgK ^ f) << 3),
                           &smem_s[pb * 4096 + j * 512]);
            }
        } else {
            #pragma unroll
            for (int jj = 0; jj < 2; jj++) {
                const int j = (wid - 4) * 2 + jj;
                const int dim = j * 4 + sdim;
                load_lds16(Vb + (size_t)dim * SEQ + s0 + ((sgV ^ (dim & 7)) << 3),
                           &smem_s[12288 + pb * 4096 + j * 512]);
            }
            if (wid == 7 && lane < 32)
                load_lds16(Tb + s0 + lane * 4, Tf + pb * 128);
        }
    };

    // QK + exp + pack for one 32-key sub s; results into carry refs.
    auto subQK = [&](int pb, int s, short8& o_pfA, short8& o_pfB,
                     short8& o_vf0, short8& o_vf1) {
        const short8 kf0 = *(const short8*)&smem_s[pb * 4096 + s * 1024 + kA];
        const short8 kf1 = *(const short8*)&smem_s[pb * 4096 + s * 1024 + kB];
        o_vf0 = *(const short8*)&smem_s[12288 + pb * 4096 + (vbase0 ^ (s << 5))];
        o_vf1 = *(const short8*)&smem_s[12288 + pb * 4096 + (vbase1 ^ (s << 5))];
        const f32x4 c0 = *(const f32x4*)&Tf[pb * 128 + s * 32 + quad * 8];
        const f32x4 c1 = *(const f32x4*)&Tf[pb * 128 + s * 32 + quad * 8 + 4];

        const f32x4 sA0 = __builtin_amdgcn_mfma_f32_16x16x32_bf16(kf0, qfA, c0, 0, 0, 0);
        const f32x4 sA1 = __builtin_amdgcn_mfma_f32_16x16x32_bf16(kf1, qfA, c1, 0, 0, 0);
        const f32x4 sB0 = __builtin_amdgcn_mfma_f32_16x16x32_bf16(kf0, qfB, c0, 0, 0, 0);
        const f32x4 sB1 = __builtin_amdgcn_mfma_f32_16x16x32_bf16(kf1, qfB, c1, 0, 0, 0);

        union { unsigned int u[4]; short8 s8; } pfA, pfB;
        {
            float p0 = exp2_raw(sA0[0]), p1 = exp2_raw(sA0[1]);
            float p2 = exp2_raw(sA0[2]), p3 = exp2_raw(sA0[3]);
            float p4 = exp2_raw(sA1[0]), p5 = exp2_raw(sA1[1]);
            float p6 = exp2_raw(sA1[2]), p7 = exp2_raw(sA1[3]);
            pfA.u[0] = pk_bf16(p0, p1);
            pfA.u[1] = pk_bf16(p2, p3);
            pfA.u[2] = pk_bf16(p4, p5);
            pfA.u[3] = pk_bf16(p6, p7);
        }
        {
            float p0 = exp2_raw(sB0[0]), p1 = exp2_raw(sB0[1]);
            float p2 = exp2_raw(sB0[2]), p3 = exp2_raw(sB0[3]);
            float p4 = exp2_raw(sB1[0]), p5 = exp2_raw(sB1[1]);
            float p6 = exp2_raw(sB1[2]), p7 = exp2_raw(sB1[3]);
            pfB.u[0] = pk_bf16(p0, p1);
            pfB.u[1] = pk_bf16(p2, p3);
            pfB.u[2] = pk_bf16(p4, p5);
            pfB.u[3] = pk_bf16(p6, p7);
        }
        o_pfA = pfA.s8;
        o_pfB = pfB.s8;
    };

    // deferred PV: 12 register-only MFMAs consuming the carry state.
    auto PV = [&]() {
        laccA = __builtin_amdgcn_mfma_f32_16x16x32_bf16(ones.s, d_pfA0, laccA, 0, 0, 0);
        laccB = __builtin_amdgcn_mfma_f32_16x16x32_bf16(ones.s, d_pfB0, laccB, 0, 0, 0);
        oA0   = __builtin_amdgcn_mfma_f32_16x16x32_bf16(d_vf00, d_pfA0, oA0,   0, 0, 0);
        oA1   = __builtin_amdgcn_mfma_f32_16x16x32_bf16(d_vf01, d_pfA0, oA1,   0, 0, 0);
        oB0   = __builtin_amdgcn_mfma_f32_16x16x32_bf16(d_vf00, d_pfB0, oB0,   0, 0, 0);
        oB1   = __builtin_amdgcn_mfma_f32_16x16x32_bf16(d_vf01, d_pfB0, oB1,   0, 0, 0);
        laccA = __builtin_amdgcn_mfma_f32_16x16x32_bf16(ones.s, d_pfA1, laccA, 0, 0, 0);
        laccB = __builtin_amdgcn_mfma_f32_16x16x32_bf16(ones.s, d_pfB1, laccB, 0, 0, 0);
        oA0   = __builtin_amdgcn_mfma_f32_16x16x32_bf16(d_vf10, d_pfA1, oA0,   0, 0, 0);
        oA1   = __builtin_amdgcn_mfma_f32_16x16x32_bf16(d_vf11, d_pfA1, oA1,   0, 0, 0);
        oB0   = __builtin_amdgcn_mfma_f32_16x16x32_bf16(d_vf10, d_pfB1, oB0,   0, 0, 0);
        oB1   = __builtin_amdgcn_mfma_f32_16x16x32_bf16(d_vf11, d_pfB1, oB1,   0, 0, 0);
    };

    // prologue: prefetch chunks 0 and 1
    stage(0, 0);
    stage(1, 1);

    // peeled round 0 (rb=0, sb=2): no deferred PV yet
    if (wid == 7)
        asm volatile("s_waitcnt vmcnt(3) lgkmcnt(0)" ::: "memory");
    else
        asm volatile("s_waitcnt vmcnt(2) lgkmcnt(0)" ::: "memory");
    __builtin_amdgcn_s_barrier();
    __builtin_amdgcn_sched_barrier(0);
    stage(2, 2);
    __builtin_amdgcn_sched_barrier(0);
    subQK(0, shalf * 2,     d_pfA0, d_pfB0, d_vf00, d_vf01);
    subQK(0, shalf * 2 + 1, d_pfA1, d_pfB1, d_vf10, d_vf11);

    int rb = 1;          // read buffer  = ch % 3
    int sb = 0;          // stage buffer = (ch+2) % 3
    for (int ch = 1; ch < SEQ / 128; ++ch) {
        // wait for MY stage(ch) loads (the newer stage(ch+1)'s 2-3 ops stay
        // in flight); lgkmcnt(0): my LDS reads of buf[(ch-1)%3] are done.
        if (wid == 7)
            asm volatile("s_waitcnt vmcnt(3) lgkmcnt(0)" ::: "memory");
        else
            asm volatile("s_waitcnt vmcnt(2) lgkmcnt(0)" ::: "memory");
        __builtin_amdgcn_s_barrier();
        __builtin_amdgcn_sched_barrier(0);
        stage((ch + 2) & 31, sb);        // overwrite buf[(ch-1)%3]
        __builtin_amdgcn_sched_barrier(0);
        PV();                            // deferred round ch-1 (regs only)
        subQK(rb, shalf * 2,     d_pfA0, d_pfB0, d_vf00, d_vf01);
        subQK(rb, shalf * 2 + 1, d_pfA1, d_pfB1, d_vf10, d_vf11);
        rb = (rb == 2) ? 0 : rb + 1;
        sb = (sb == 2) ? 0 : sb + 1;
    }
    PV();                                // final deferred round

    // drain ALL in-flight staging (wrap prefetches included) before reusing
    // the K LDS region as combine scratch.
    asm volatile("s_waitcnt vmcnt(0) lgkmcnt(0)" ::: "memory");
    __builtin_amdgcn_s_barrier();

    float* CS = (float*)smem;            // 256 slots x 20 floats = 20480 B
    if (wid >= 4) {
        const int slot = ((cwid * 64) + lane) * 20;
        *(f32x4*)&CS[slot + 0]  = oA0;
        *(f32x4*)&CS[slot + 4]  = oA1;
        *(f32x4*)&CS[slot + 8]  = oB0;
        *(f32x4*)&CS[slot + 12] = oB1;
        CS[slot + 16] = laccA[0];
        CS[slot + 17] = laccB[0];
    }
    asm volatile("s_waitcnt lgkmcnt(0)" ::: "memory");
    __builtin_amdgcn_s_barrier();
    if (wid < 4) {
        const int slot = ((cwid * 64) + lane) * 20;
        const f32x4 pA0 = *(const f32x4*)&CS[slot + 0];
        const f32x4 pA1 = *(const f32x4*)&CS[slot + 4];
        const f32x4 pB0 = *(const f32x4*)&CS[slot + 8];
        const f32x4 pB1 = *(const f32x4*)&CS[slot + 12];
        const float invA = 1.0f / (laccA[0] + CS[slot + 16]);
        const float invB = 1.0f / (laccB[0] + CS[slot + 17]);
        oA0 += pA0; oA1 += pA1; oB0 += pB0; oB1 += pB1;

        float* opA = O + ((size_t)(b * SEQ) + qrow + c) * D_MODEL + h * DIM_HEAD + quad * 4;
        float* opB = O + ((size_t)(b * SEQ) + qrow + 16 + c) * D_MODEL + h * DIM_HEAD + quad * 4;
        *(float4*)opA        = make_float4(oA0[0]*invA, oA0[1]*invA, oA0[2]*invA, oA0[3]*invA);
        *(float4*)(opA + 16) = make_float4(oA1[0]*invA, oA1[1]*invA, oA1[2]*invA, oA1[3]*invA);
        *(float4*)opB        = make_float4(oB0[0]*invB, oB0[1]*invB, oB0[2]*invB, oB0[3]*invB);
        *(float4*)(opB + 16) = make_float4(oB1[0]*invB, oB1[1]*invB, oB1[2]*invB, oB1[3]*invB);
    }
}

// ---------------------------------------------------------------------------
// Kernel 3: residual add + LayerNorm IN PLACE on d_out (fp32 -> fp32).
// ---------------------------------------------------------------------------
__global__ __launch_bounds__(256) void ln_kernel(
    float* AO,                     // aliased read A / write out — no restrict
    const float* __restrict__ x,
    const float* __restrict__ gamma, const float* __restrict__ beta)
{
    const int lane = threadIdx.x & 63;
    const int wid  = threadIdx.x >> 6;
    const size_t row = (size_t)blockIdx.x * 4 + wid;

    const float4 a  = ((const float4*)(AO + row * D_MODEL))[lane];
    const float4 xv = ((const float4*)(x + row * D_MODEL))[lane];
    float hv[4];
    hv[0] = a.x + xv.x;
    hv[1] = a.y + xv.y;
    hv[2] = a.z + xv.z;
    hv[3] = a.w + xv.w;

    float s = hv[0] + hv[1] + hv[2] + hv[3];
    #pragma unroll
    for (int off = 32; off > 0; off >>= 1) s += __shfl_xor(s, off, 64);
    const float mu = s * (1.0f / D_MODEL);

    float d0 = hv[0]-mu, d1 = hv[1]-mu, d2 = hv[2]-mu, d3 = hv[3]-mu;
    float ss = d0*d0 + d1*d1 + d2*d2 + d3*d3;
    #pragma unroll
    for (int off = 32; off > 0; off >>= 1) ss += __shfl_xor(ss, off, 64);
    const float rs = rsqrtf(ss * (1.0f / D_MODEL) + LN_EPS);

    const float4 g  = ((const float4*)gamma)[lane];
    const float4 bb = ((const float4*)beta)[lane];
    float4 y;
    y.x = g.x * d0 * rs + bb.x;
    y.y = g.y * d1 * rs + bb.y;
    y.z = g.z * d2 * rs + bb.z;
    y.w = g.w * d3 * rs + bb.w;
    ((float4*)(AO + row * D_MODEL))[lane] = y;
}

// ---------------------------------------------------------------------------
extern "C" void kernel_launch(void* const* d_in, const int* in_sizes, int n_in,
                              void* d_out, int out_size, void* d_ws, size_t ws_size,
                              hipStream_t stream)
{
    const float* x     = (const float*)d_in[0];
    const float* pad   = (const float*)d_in[1];
    const float* Wq    = (const float*)d_in[2];
    const float* bq    = (const float*)d_in[3];
    const float* Wk    = (const float*)d_in[4];
    const float* bk    = (const float*)d_in[5];
    const float* Wv    = (const float*)d_in[6];
    const float* bv    = (const float*)d_in[7];
    const float* gamma = (const float*)d_in[8];
    const float* beta  = (const float*)d_in[9];

    const size_t elems = (size_t)NROWS * D_MODEL;       // 2M
    unsigned short* Qh = (unsigned short*)d_ws;          // 4 MB
    unsigned short* Kh = Qh + elems;                     // 4 MB
    unsigned short* Vt = Kh + elems;                     // 4 MB
    float* T2 = (float*)(Vt + elems);                    // 32 KB
    unsigned short* Wt = (unsigned short*)(T2 + NROWS);  // 768x256 bf16, 384 KB
    float* biasc = (float*)(Wt + 768 * 256);             // 3 KB
    float* AO = (float*)d_out;                           // attn out + final out

    prep_kernel<<<80, 256, 0, stream>>>(Wq, Wk, Wv, bq, bk, bv, pad,
                                        Wt, biasc, T2);
    qkv_mfma_kernel<<<(NROWS / 64) * 8, 256, 0, stream>>>(x, Wt, biasc,
                                                          Qh, Kh, Vt);
    attn_mfma_kernel<<<BATCH * NUM_HEADS * (SEQ / 128), 512, 0, stream>>>(
        Qh, Kh, Vt, T2, AO);
    ln_kernel<<<NROWS / 4, 256, 0, stream>>>(AO, x, gamma, beta);
}